// Round 7
// baseline (943.690 us; speedup 1.0000x reference)
//
#include <hip/hip_runtime.h>
#include <cstdint>
#include <cstddef>

// ============================================================================
// ResMLP fused kernel for MI355X (gfx950) — round 7
//
//  - prep (as r6): weights -> 38 LDS-ready images ws[img][160n][168k] bf16
//      img 0..4 embed (k pad 784->800), 5..36 layers, 37 head (n>=10 zero).
//  - main: 1024 blocks x 256 thr, 2 blocks/CU (75.8 KB LDS), 4 waves/SIMD.
//    Block = 64 rows through whole net; 4 waves = 2(mg:32r) x 2(ng:80c).
//    Residual fp32 in regs. SINGLE W panel buffer in LDS:
//      panel p top:   issue global->reg loads of image p+1 (L2 latency hidden)
//      inner 5 chunks: pure ds_read + MFMA (no vmem waits)
//      barrier; boundary (H writeback); reg->LDS ds_write of p+1; barrier
//    Sibling block on the CU runs anti-phased -> barriers/staging overlapped.
// ============================================================================

typedef __attribute__((ext_vector_type(8))) short bfrag8;   // 8 x bf16
typedef __attribute__((ext_vector_type(4))) float facc4;    // 4 x f32

#define MFMA16(a, b, c) __builtin_amdgcn_mfma_f32_16x16x32_bf16((a), (b), (c), 0, 0, 0)

#define NIMG       38
#define IMG_ELEMS  27136          // 160*168 + 256 pad (uint16)
#define IMG_BYTES  54272
#define STG_U4     3360           // 160*336 B staged = 3360 uint4
#define HS_ELEMS   10752          // 64*168

static __device__ __forceinline__ uint16_t f2bf16u(float v) {
    uint32_t u = __builtin_bit_cast(uint32_t, v);
    uint32_t r = u + 0x7FFFu + ((u >> 16) & 1u);
    return (uint16_t)(r >> 16);
}
static __device__ __forceinline__ uint32_t pack2_bf16(float lo, float hi) {
    return (uint32_t)f2bf16u(lo) | ((uint32_t)f2bf16u(hi) << 16);
}
static __device__ __forceinline__ uint32_t rtn_bits(float f) {
    return __builtin_bit_cast(uint32_t, f) + 0x8000u;
}

// ---------------------------------------------------------------------------
// prep: transpose + cast weights into LDS-image format (r6 layout).
// Grid 950 = 38 images x 25 (5 k-tiles x 5 n-tiles), 256 thr.
// ---------------------------------------------------------------------------
__global__ __launch_bounds__(256) void resmlp_prep(
    const float* __restrict__ embed_w, const float* __restrict__ layer_w,
    const float* __restrict__ head_w, uint16_t* __restrict__ ws)
{
    int b = blockIdx.x;
    int img = b / 25, t = b % 25;
    int rt = t / 5, ct = t % 5;           // k-tile, n-tile
    int tx = threadIdx.x & 31, ty = threadIdx.x >> 5;

    __shared__ float tile[32][33];
#pragma unroll
    for (int j = 0; j < 4; ++j) {
        int k = rt * 32 + ty + j * 8;     // local k 0..159
        int n = ct * 32 + tx;             // n 0..159
        float v;
        if (img < 5) {
            int kg = img * 160 + k;
            v = (kg < 784) ? embed_w[(size_t)kg * 160 + n] : 0.f;
        } else if (img < 37) {
            v = layer_w[(size_t)(img - 5) * 25600 + (size_t)k * 160 + n];
        } else {
            v = (n < 10) ? head_w[k * 10 + n] : 0.f;
        }
        tile[ty + j * 8][tx] = v;
    }
    __syncthreads();
    uint16_t* dst = ws + (size_t)img * IMG_ELEMS;
#pragma unroll
    for (int j = 0; j < 4; ++j) {
        int n = ct * 32 + ty + j * 8;
        int k = rt * 32 + tx;
        dst[n * 168 + k] = f2bf16u(tile[tx][ty + j * 8]);
    }
}

// ---------------------------------------------------------------------------
// stage 64 rows x 160-col chunk of x (fp32 HBM) -> Hs bf16 (stride 168)
// ---------------------------------------------------------------------------
__device__ __forceinline__ void stage_x(const float* __restrict__ x,
                                        uint16_t* Hs, int r0, int tid, int g)
{
    const int row = tid >> 2;          // 0..63
    const int kc  = g * 160;
    const float* xr = x + (size_t)(r0 + row) * 784 + kc;
#pragma unroll
    for (int j = 0; j < 10; ++j) {
        int c4 = (tid & 3) + j * 4;    // float4 index 0..39
        float4 v = (kc + c4 * 4 < 784) ? *(const float4*)(xr + c4 * 4)
                                       : make_float4(0.f, 0.f, 0.f, 0.f);
        uint2 u;
        u.x = pack2_bf16(v.x, v.y);
        u.y = pack2_bf16(v.z, v.w);
        *(uint2*)((char*)Hs + row * 336 + c4 * 8) = u;
    }
}

// ---------------------------------------------------------------------------
__global__ __launch_bounds__(256, 2) void resmlp_main(
    const float* __restrict__ x,
    const float* __restrict__ embed_b,
    const float* __restrict__ head_b,
    const uint16_t* __restrict__ ws,
    float* __restrict__ out)
{
    extern __shared__ __align__(16) uint16_t lds[];
    uint16_t* Hs = lds;                 // 10752 elems (21504 B)
    uint16_t* Wb = lds + HS_ELEMS;      // 27136 elems (54272 B)

    const int tid  = threadIdx.x;
    const int lane = tid & 63;
    const int wave = tid >> 6;         // 0..3
    const int mg = wave >> 1;          // 0..1  row group (32 rows)
    const int ng = wave & 1;           // 0..1  col group (80 cols)
    const int q  = lane >> 4;          // 0..3
    const int ln = lane & 15;          // 0..15
    const int NB = ng * 80;
    const int r0 = blockIdx.x * 64;
    const bool oddl = (ln & 1) != 0;
    const uint32_t psel = oddl ? 0x03020706u : 0x07060302u;

    float bias[5];
#pragma unroll
    for (int nt = 0; nt < 5; ++nt) bias[nt] = embed_b[NB + nt * 16 + ln];
    const float hb = (ln < 10) ? head_b[ln] : 0.f;

    facc4 acc[2][5];
    facc4 resid[2][5];
    uint4 st[14];                      // staging registers for next W image
#pragma unroll
    for (int mt = 0; mt < 2; ++mt)
#pragma unroll
        for (int nt = 0; nt < 5; ++nt) acc[mt][nt] = (facc4){0.f, 0.f, 0.f, 0.f};

    const char* wsb = (const char*)ws;

    // ---- prologue: stage x group 0; stage W image 0 via regs ----
    stage_x(x, Hs, r0, tid, 0);
#pragma unroll
    for (int j = 0; j < 14; ++j) {
        int idx = tid + j * 256;
        if (idx < STG_U4) st[j] = *(const uint4*)(wsb + idx * 16);
    }
#pragma unroll
    for (int j = 0; j < 14; ++j) {
        int idx = tid + j * 256;
        if (idx < STG_U4) *(uint4*)((char*)Wb + idx * 16) = st[j];
    }
    __syncthreads();

    const int abase = (mg * 32 + ln) * 168 + q * 8;   // A elem offset in Hs
    const int bbase = (NB + ln) * 168 + q * 8;        // B elem offset in Wb
    const int wb_base = (mg * 32 + q * 4 + (ln & 1)) * 336 + (NB + (ln & ~1)) * 2;

    for (int p = 0; p < 38; ++p) {
        // ---- issue global->reg loads of image p+1 (consumed after barrier) --
        if (p < 37) {
            const char* src = wsb + (size_t)(p + 1) * IMG_BYTES;
#pragma unroll
            for (int j = 0; j < 14; ++j) {
                int idx = tid + j * 256;
                if (idx < STG_U4) st[j] = *(const uint4*)(src + idx * 16);
            }
        }

        // ---- compute 5 chunks from Wb (pure LDS + MFMA) ----
#pragma unroll
        for (int k = 0; k < 5; ++k) {
            bfrag8 a0 = *(const bfrag8*)(Hs + abase + 0 * (16 * 168) + k * 32);
            bfrag8 a1 = *(const bfrag8*)(Hs + abase + 1 * (16 * 168) + k * 32);
#pragma unroll
            for (int nt = 0; nt < 5; ++nt) {
                bfrag8 bf = *(const bfrag8*)(Wb + bbase + nt * (16 * 168) + k * 32);
                acc[0][nt] = MFMA16(a0, bf, acc[0][nt]);
                acc[1][nt] = MFMA16(a1, bf, acc[1][nt]);
            }
        }

        if (p == 37) {
            // head epilogue + store (no LDS involved)
            if (ng == 0) {
#pragma unroll
                for (int mt = 0; mt < 2; ++mt)
#pragma unroll
                    for (int r = 0; r < 4; ++r) {
                        int row = r0 + mg * 32 + mt * 16 + q * 4 + r;
                        if (ln < 10) out[row * 10 + ln] = acc[mt][0][r] + hb;
                    }
            }
            break;
        }

        __syncthreads();               // all reads of Hs/Wb for panel p done

        // ---- boundary work ----
        if (p < 4) {
            stage_x(x, Hs, r0, tid, p + 1);
        } else {
            if (p == 4) {
#pragma unroll
                for (int mt = 0; mt < 2; ++mt)
#pragma unroll
                    for (int nt = 0; nt < 5; ++nt)
#pragma unroll
                        for (int r = 0; r < 4; ++r)
                            resid[mt][nt][r] = acc[mt][nt][r] + bias[nt];
            } else {
#pragma unroll
                for (int mt = 0; mt < 2; ++mt)
#pragma unroll
                    for (int nt = 0; nt < 5; ++nt)
#pragma unroll
                        for (int r = 0; r < 4; ++r)
                            resid[mt][nt][r] += fmaxf(acc[mt][nt][r], 0.f);
            }
#pragma unroll
            for (int mt = 0; mt < 2; ++mt) {
#pragma unroll
                for (int nt = 0; nt < 5; ++nt) {
                    acc[mt][nt] = (facc4){0.f, 0.f, 0.f, 0.f};
#pragma unroll
                    for (int pr = 0; pr < 2; ++pr) {
                        const int rl = pr * 2;
                        float a  = oddl ? resid[mt][nt][rl + 1] : resid[mt][nt][rl];
                        float bx = oddl ? resid[mt][nt][rl]     : resid[mt][nt][rl + 1];
                        uint32_t br = rtn_bits(bx);
                        uint32_t pb = (uint32_t)__builtin_amdgcn_mov_dpp(
                            (int)br, 0xB1, 0xF, 0xF, true);        // pair swap
                        uint32_t pk = __builtin_amdgcn_perm(pb, rtn_bits(a), psel);
                        *(uint32_t*)((char*)Hs + wb_base +
                                     mt * (16 * 336) + rl * 336 + nt * 32) = pk;
                    }
                }
            }
        }

        // ---- commit staged image p+1 to Wb (no reader active) ----
#pragma unroll
        for (int j = 0; j < 14; ++j) {
            int idx = tid + j * 256;
            if (idx < STG_U4) *(uint4*)((char*)Wb + idx * 16) = st[j];
        }
        __syncthreads();               // Wb + Hs ready for panel p+1
    }
}

// ---------------------------------------------------------------------------
extern "C" void kernel_launch(void* const* d_in, const int* in_sizes, int n_in,
                              void* d_out, int out_size, void* d_ws, size_t ws_size,
                              hipStream_t stream) {
    (void)in_sizes; (void)n_in; (void)out_size; (void)ws_size;
    const float* x       = (const float*)d_in[0];
    const float* embed_w = (const float*)d_in[1];
    const float* embed_b = (const float*)d_in[2];
    const float* layer_w = (const float*)d_in[3];
    const float* head_w  = (const float*)d_in[4];
    const float* head_b  = (const float*)d_in[5];
    float* out = (float*)d_out;

    uint16_t* ws = (uint16_t*)d_ws;   // 38 * 27136 u16 = 2.06 MB

    const int dynLds = (HS_ELEMS + IMG_ELEMS) * 2;   // 75776 B
    (void)hipFuncSetAttribute((const void*)resmlp_main,
                              hipFuncAttributeMaxDynamicSharedMemorySize, dynLds);

    resmlp_prep<<<950, 256, 0, stream>>>(embed_w, layer_w, head_w, ws);
    resmlp_main<<<1024, 256, dynLds, stream>>>(x, embed_b, head_b, ws, out);
}

// Round 8
// 453.879 us; speedup vs baseline: 2.0792x; 2.0792x over previous
//
#include <hip/hip_runtime.h>
#include <cstdint>
#include <cstddef>

// ============================================================================
// ResMLP fused kernel for MI355X (gfx950) — round 8
//
//  - prep (as r6/r7): weights -> 38 LDS-ready images ws[img][160n][168k] bf16
//      img 0..4 embed (k pad 784->800), 5..36 layers, 37 head (n>=10 zero).
//  - main: 1024 blocks x 256 thr, 2 blocks/CU (75.8 KB LDS each).
//    Block = 64 rows through whole net; 4 waves = 2(mg:32r) x 2(ng:80c).
//    Residual fp32 in regs. SINGLE W panel buffer in LDS, staged with
//    global_load_lds (L2 -> LDS direct, NO register round-trip -> no spill,
//    r7's 2 GB scratch thrash eliminated) inside the boundary window:
//      compute 5 chunks (pure ds_read+MFMA) | barrier |
//      issue 53x1KB global_load_lds of image p+1 ; boundary VALU (writeback)
//      | barrier (drains vmcnt) | next panel
//    Two independent blocks/CU self-anti-phase: while one drains/stages the
//    other computes -> DS pipe and MFMA stay fed (r6's single 8-wave block
//    stalled ALL waves at every barrier).
// ============================================================================

typedef __attribute__((ext_vector_type(8))) short bfrag8;   // 8 x bf16
typedef __attribute__((ext_vector_type(4))) float facc4;    // 4 x f32

#define MFMA16(a, b, c) __builtin_amdgcn_mfma_f32_16x16x32_bf16((a), (b), (c), 0, 0, 0)

#define NIMG       38
#define IMG_ELEMS  27136          // 160*168 + 256 pad (uint16)
#define IMG_BYTES  54272          // 53 x 1024
#define HS_ELEMS   10752          // 64*168

static __device__ __forceinline__ uint16_t f2bf16u(float v) {
    uint32_t u = __builtin_bit_cast(uint32_t, v);
    uint32_t r = u + 0x7FFFu + ((u >> 16) & 1u);
    return (uint16_t)(r >> 16);
}
static __device__ __forceinline__ uint32_t pack2_bf16(float lo, float hi) {
    return (uint32_t)f2bf16u(lo) | ((uint32_t)f2bf16u(hi) << 16);
}
static __device__ __forceinline__ uint32_t rtn_bits(float f) {
    return __builtin_bit_cast(uint32_t, f) + 0x8000u;
}
// async global->LDS, 16B per lane; lds dest = wave-uniform base + lane*16
static __device__ __forceinline__ void gl_lds16(const void* g, void* l) {
    __builtin_amdgcn_global_load_lds(
        (const __attribute__((address_space(1))) uint32_t*)g,
        (__attribute__((address_space(3))) uint32_t*)l, 16, 0, 0);
}

// ---------------------------------------------------------------------------
// prep: transpose + cast weights into LDS-image format.
// Grid 950 = 38 images x 25 (5 k-tiles x 5 n-tiles), 256 thr.
// ---------------------------------------------------------------------------
__global__ __launch_bounds__(256) void resmlp_prep(
    const float* __restrict__ embed_w, const float* __restrict__ layer_w,
    const float* __restrict__ head_w, uint16_t* __restrict__ ws)
{
    int b = blockIdx.x;
    int img = b / 25, t = b % 25;
    int rt = t / 5, ct = t % 5;           // k-tile, n-tile
    int tx = threadIdx.x & 31, ty = threadIdx.x >> 5;

    __shared__ float tile[32][33];
#pragma unroll
    for (int j = 0; j < 4; ++j) {
        int k = rt * 32 + ty + j * 8;     // local k 0..159
        int n = ct * 32 + tx;             // n 0..159
        float v;
        if (img < 5) {
            int kg = img * 160 + k;
            v = (kg < 784) ? embed_w[(size_t)kg * 160 + n] : 0.f;
        } else if (img < 37) {
            v = layer_w[(size_t)(img - 5) * 25600 + (size_t)k * 160 + n];
        } else {
            v = (n < 10) ? head_w[k * 10 + n] : 0.f;
        }
        tile[ty + j * 8][tx] = v;
    }
    __syncthreads();
    uint16_t* dst = ws + (size_t)img * IMG_ELEMS;
#pragma unroll
    for (int j = 0; j < 4; ++j) {
        int n = ct * 32 + ty + j * 8;
        int k = rt * 32 + tx;
        dst[n * 168 + k] = f2bf16u(tile[tx][ty + j * 8]);
    }
}

// ---------------------------------------------------------------------------
// stage 64 rows x 160-col chunk of x (fp32 HBM) -> Hs bf16 (stride 168)
// ---------------------------------------------------------------------------
__device__ __forceinline__ void stage_x(const float* __restrict__ x,
                                        uint16_t* Hs, int r0, int tid, int g)
{
    const int row = tid >> 2;          // 0..63
    const int kc  = g * 160;
    const float* xr = x + (size_t)(r0 + row) * 784 + kc;
#pragma unroll
    for (int j = 0; j < 10; ++j) {
        int c4 = (tid & 3) + j * 4;    // float4 index 0..39
        float4 v = (kc + c4 * 4 < 784) ? *(const float4*)(xr + c4 * 4)
                                       : make_float4(0.f, 0.f, 0.f, 0.f);
        uint2 u;
        u.x = pack2_bf16(v.x, v.y);
        u.y = pack2_bf16(v.z, v.w);
        *(uint2*)((char*)Hs + row * 336 + c4 * 8) = u;
    }
}

// ---------------------------------------------------------------------------
__global__ __launch_bounds__(256, 2) void resmlp_main(
    const float* __restrict__ x,
    const float* __restrict__ embed_b,
    const float* __restrict__ head_b,
    const uint16_t* __restrict__ ws,
    float* __restrict__ out)
{
    extern __shared__ __align__(16) uint16_t lds[];
    uint16_t* Hs = lds;                 // 10752 elems (21504 B)
    uint16_t* Wb = lds + HS_ELEMS;      // 27136 elems (54272 B)

    const int tid  = threadIdx.x;
    const int lane = tid & 63;
    const int wave = tid >> 6;         // 0..3
    const int mg = wave >> 1;          // 0..1  row group (32 rows)
    const int ng = wave & 1;           // 0..1  col group (80 cols)
    const int q  = lane >> 4;          // 0..3
    const int ln = lane & 15;          // 0..15
    const int NB = ng * 80;
    const int r0 = blockIdx.x * 64;
    const bool oddl = (ln & 1) != 0;
    const uint32_t psel = oddl ? 0x03020706u : 0x07060302u;

    float bias[5];
#pragma unroll
    for (int nt = 0; nt < 5; ++nt) bias[nt] = embed_b[NB + nt * 16 + ln];
    const float hb = (ln < 10) ? head_b[ln] : 0.f;

    facc4 acc[2][5];
    facc4 resid[2][5];
#pragma unroll
    for (int mt = 0; mt < 2; ++mt)
#pragma unroll
        for (int nt = 0; nt < 5; ++nt) acc[mt][nt] = (facc4){0.f, 0.f, 0.f, 0.f};

    const char* wsb = (const char*)ws;
    const int lb = lane * 16;          // lane byte offset within a 1KB call

    // ---- prologue: stage x group 0 + W image 0 into Wb ----
    stage_x(x, Hs, r0, tid, 0);
#pragma unroll
    for (int i = 0; i < 14; ++i) {
        int idx = wave + i * 4;
        if (idx < 53)
            gl_lds16(wsb + idx * 1024 + lb, (char*)Wb + idx * 1024 + lb);
    }
    __syncthreads();                   // drains vmcnt(0) too

    const int abase = (mg * 32 + ln) * 168 + q * 8;   // A elem offset in Hs
    const int bbase = (NB + ln) * 168 + q * 8;        // B elem offset in Wb
    const int wb_base = (mg * 32 + q * 4 + (ln & 1)) * 336 + (NB + (ln & ~1)) * 2;

    for (int p = 0; p < 38; ++p) {
        // ---- compute 5 chunks from Wb (pure LDS + MFMA, no vmem) ----
#pragma unroll
        for (int k = 0; k < 5; ++k) {
            bfrag8 a0 = *(const bfrag8*)(Hs + abase + 0 * (16 * 168) + k * 32);
            bfrag8 a1 = *(const bfrag8*)(Hs + abase + 1 * (16 * 168) + k * 32);
#pragma unroll
            for (int nt = 0; nt < 5; ++nt) {
                bfrag8 bf = *(const bfrag8*)(Wb + bbase + nt * (16 * 168) + k * 32);
                acc[0][nt] = MFMA16(a0, bf, acc[0][nt]);
                acc[1][nt] = MFMA16(a1, bf, acc[1][nt]);
            }
        }

        if (p == 37) {
            // head epilogue + store (no LDS involved)
            if (ng == 0) {
#pragma unroll
                for (int mt = 0; mt < 2; ++mt)
#pragma unroll
                    for (int r = 0; r < 4; ++r) {
                        int row = r0 + mg * 32 + mt * 16 + q * 4 + r;
                        if (ln < 10) out[row * 10 + ln] = acc[mt][0][r] + hb;
                    }
            }
            break;
        }

        __syncthreads();               // all reads of Hs/Wb for panel p done

        // ---- issue async staging of image p+1 straight into Wb ----
        {
            const char* src = wsb + (size_t)(p + 1) * IMG_BYTES;
#pragma unroll
            for (int i = 0; i < 14; ++i) {
                int idx = wave + i * 4;
                if (idx < 53)
                    gl_lds16(src + idx * 1024 + lb, (char*)Wb + idx * 1024 + lb);
            }
        }

        // ---- boundary VALU work (overlaps the in-flight staging) ----
        if (p < 4) {
            stage_x(x, Hs, r0, tid, p + 1);
        } else {
            if (p == 4) {
#pragma unroll
                for (int mt = 0; mt < 2; ++mt)
#pragma unroll
                    for (int nt = 0; nt < 5; ++nt)
#pragma unroll
                        for (int r = 0; r < 4; ++r)
                            resid[mt][nt][r] = acc[mt][nt][r] + bias[nt];
            } else {
#pragma unroll
                for (int mt = 0; mt < 2; ++mt)
#pragma unroll
                    for (int nt = 0; nt < 5; ++nt)
#pragma unroll
                        for (int r = 0; r < 4; ++r)
                            resid[mt][nt][r] += fmaxf(acc[mt][nt][r], 0.f);
            }
#pragma unroll
            for (int mt = 0; mt < 2; ++mt) {
#pragma unroll
                for (int nt = 0; nt < 5; ++nt) {
                    acc[mt][nt] = (facc4){0.f, 0.f, 0.f, 0.f};
#pragma unroll
                    for (int pr = 0; pr < 2; ++pr) {
                        const int rl = pr * 2;
                        float a  = oddl ? resid[mt][nt][rl + 1] : resid[mt][nt][rl];
                        float bx = oddl ? resid[mt][nt][rl]     : resid[mt][nt][rl + 1];
                        uint32_t br = rtn_bits(bx);
                        uint32_t pb = (uint32_t)__builtin_amdgcn_mov_dpp(
                            (int)br, 0xB1, 0xF, 0xF, true);        // pair swap
                        uint32_t pk = __builtin_amdgcn_perm(pb, rtn_bits(a), psel);
                        *(uint32_t*)((char*)Hs + wb_base +
                                     mt * (16 * 336) + rl * 336 + nt * 32) = pk;
                    }
                }
            }
        }

        __syncthreads();               // drains vmcnt -> Wb holds image p+1
    }
}

// ---------------------------------------------------------------------------
extern "C" void kernel_launch(void* const* d_in, const int* in_sizes, int n_in,
                              void* d_out, int out_size, void* d_ws, size_t ws_size,
                              hipStream_t stream) {
    (void)in_sizes; (void)n_in; (void)out_size; (void)ws_size;
    const float* x       = (const float*)d_in[0];
    const float* embed_w = (const float*)d_in[1];
    const float* embed_b = (const float*)d_in[2];
    const float* layer_w = (const float*)d_in[3];
    const float* head_w  = (const float*)d_in[4];
    const float* head_b  = (const float*)d_in[5];
    float* out = (float*)d_out;

    uint16_t* ws = (uint16_t*)d_ws;   // 38 * 27136 u16 = 2.06 MB

    const int dynLds = (HS_ELEMS + IMG_ELEMS) * 2;   // 75776 B
    (void)hipFuncSetAttribute((const void*)resmlp_main,
                              hipFuncAttributeMaxDynamicSharedMemorySize, dynLds);

    resmlp_prep<<<950, 256, 0, stream>>>(embed_w, layer_w, head_w, ws);
    resmlp_main<<<1024, 256, dynLds, stream>>>(x, embed_b, head_b, ws, out);
}